// Round 4
// baseline (459.711 us; speedup 1.0000x reference)
//
#include <hip/hip_runtime.h>
#include <hip/hip_bf16.h>
#include <cstdint>

typedef __bf16 bf16x8 __attribute__((ext_vector_type(8)));
typedef float floatx4 __attribute__((ext_vector_type(4)));

__device__ __forceinline__ void gl2lds16(const void* g, void* l) {
  __builtin_amdgcn_global_load_lds(
      (const __attribute__((address_space(1))) unsigned int*)g,
      (__attribute__((address_space(3))) unsigned int*)(uintptr_t)l,
      16, 0, 0);
}

// ---------------- fp32 -> bf16 convert ----------------
__global__ __launch_bounds__(256)
void cvt_kernel(const float* __restrict__ in, __hip_bfloat16* __restrict__ out, int n) {
  int i = (blockIdx.x * 256 + threadIdx.x) * 4;
  if (i >= n) return;
  const float4 v = *(const float4*)(in + i);
  out[i + 0] = __float2bfloat16(v.x);
  out[i + 1] = __float2bfloat16(v.y);
  out[i + 2] = __float2bfloat16(v.z);
  out[i + 3] = __float2bfloat16(v.w);
}

// ---------------- plain bf16 GEMM (O-proj): C[M][Nc] = A[M][K] * B[Nc][K]^T ----
__global__ __launch_bounds__(256)
void gemm_bt(const __hip_bfloat16* __restrict__ A, const __hip_bfloat16* __restrict__ Bm,
             void* __restrict__ Cp, int M, int Nc, int K, int c_fp32)
{
  __shared__ __hip_bfloat16 As[128 * 32];
  __shared__ __hip_bfloat16 Bs[128 * 32];
  const int tid = threadIdx.x;
  const int lane = tid & 63, wave = tid >> 6;
  const int wm = (wave & 1) * 64, wn = (wave >> 1) * 64;
  const int m0 = blockIdx.x * 128, n0 = blockIdx.y * 128;
  const int lrow = lane & 15, lk = (lane >> 4) * 8;
  floatx4 acc[4][4] = {};
  const int c0 = tid, c1 = tid + 256;
  const int r0 = c0 >> 2, o0 = (c0 & 3) * 8;
  const int r1 = c1 >> 2, o1 = (c1 & 3) * 8;
  for (int kt = 0; kt < K; kt += 32) {
    __syncthreads();
    gl2lds16(A + (size_t)(m0 + r0) * K + kt + o0, &As[c0 * 8]);
    gl2lds16(A + (size_t)(m0 + r1) * K + kt + o1, &As[c1 * 8]);
    gl2lds16(Bm + (size_t)(n0 + r0) * K + kt + o0, &Bs[c0 * 8]);
    gl2lds16(Bm + (size_t)(n0 + r1) * K + kt + o1, &Bs[c1 * 8]);
    __syncthreads();
    bf16x8 af[4], bfr[4];
#pragma unroll
    for (int t = 0; t < 4; t++) af[t] = *(const bf16x8*)&As[(wm + t * 16 + lrow) * 32 + lk];
#pragma unroll
    for (int t = 0; t < 4; t++) bfr[t] = *(const bf16x8*)&Bs[(wn + t * 16 + lrow) * 32 + lk];
#pragma unroll
    for (int mt = 0; mt < 4; mt++)
#pragma unroll
      for (int nt = 0; nt < 4; nt++)
        acc[mt][nt] = __builtin_amdgcn_mfma_f32_16x16x32_bf16(af[mt], bfr[nt], acc[mt][nt], 0, 0, 0);
  }
  const int lq4 = (lane >> 4) * 4;
#pragma unroll
  for (int mt = 0; mt < 4; mt++)
#pragma unroll
    for (int nt = 0; nt < 4; nt++)
#pragma unroll
      for (int r = 0; r < 4; r++) {
        const int m = m0 + wm + mt * 16 + lq4 + r;
        const int n = n0 + wn + nt * 16 + lrow;
        const float v = acc[mt][nt][r];
        if (c_fp32) ((float*)Cp)[(size_t)m * Nc + n] = v;
        else ((__hip_bfloat16*)Cp)[(size_t)m * Nc + n] = __float2bfloat16(v);
      }
}

// ---------------- QKV GEMM with fused RoPE + relayout epilogue ----------------
__global__ __launch_bounds__(256)
void gemm_qkv_fused(const __hip_bfloat16* __restrict__ A,
                    const __hip_bfloat16* __restrict__ W,
                    __hip_bfloat16* __restrict__ Qr,
                    __hip_bfloat16* __restrict__ Kr,
                    __hip_bfloat16* __restrict__ Vt)
{
  __shared__ alignas(16) char smem[16640];     // union: As+Bs (16384) | Cs 64x130 bf16 (16640)
  __shared__ float invf[64];
  __hip_bfloat16* As = (__hip_bfloat16*)smem;
  __hip_bfloat16* Bs = As + 128 * 32;
  __hip_bfloat16* Cs = (__hip_bfloat16*)smem;  // [64][130]
  const int tid = threadIdx.x;
  if (tid < 64) invf[tid] = __expf(-(float)tid * 0.14391156831212787f);  // 10000^(-t/64)
  const int lane = tid & 63, wave = tid >> 6;
  const int wm = (wave & 1) * 64, wn = (wave >> 1) * 64;
  const int m0 = blockIdx.x * 128, n0 = blockIdx.y * 128;
  const int K = 2048;
  const int lrow = lane & 15, lk = (lane >> 4) * 8;
  floatx4 acc[4][4] = {};
  const int c0 = tid, c1 = tid + 256;
  const int r0 = c0 >> 2, o0 = (c0 & 3) * 8;
  const int r1 = c1 >> 2, o1 = (c1 & 3) * 8;
  for (int kt = 0; kt < K; kt += 32) {
    __syncthreads();
    gl2lds16(A + (size_t)(m0 + r0) * K + kt + o0, &As[c0 * 8]);
    gl2lds16(A + (size_t)(m0 + r1) * K + kt + o1, &As[c1 * 8]);
    gl2lds16(W + (size_t)(n0 + r0) * K + kt + o0, &Bs[c0 * 8]);
    gl2lds16(W + (size_t)(n0 + r1) * K + kt + o1, &Bs[c1 * 8]);
    __syncthreads();
    bf16x8 af[4], bfr[4];
#pragma unroll
    for (int t = 0; t < 4; t++) af[t] = *(const bf16x8*)&As[(wm + t * 16 + lrow) * 32 + lk];
#pragma unroll
    for (int t = 0; t < 4; t++) bfr[t] = *(const bf16x8*)&Bs[(wn + t * 16 + lrow) * 32 + lk];
#pragma unroll
    for (int mt = 0; mt < 4; mt++)
#pragma unroll
      for (int nt = 0; nt < 4; nt++)
        acc[mt][nt] = __builtin_amdgcn_mfma_f32_16x16x32_bf16(af[mt], bfr[nt], acc[mt][nt], 0, 0, 0);
  }
  const int lq4 = (lane >> 4) * 4;
  const int seg = n0 >> 11;            // 0=Q 1=K 2=V
  const int h = (n0 & 2047) >> 7;
  const int b = m0 >> 11;
  const int bh = b * 16 + h;
  const int seq0 = m0 & 2047;
  const float qscale = (seg == 0) ? 0.08838834764831845f : 1.0f;
  for (int pass = 0; pass < 2; ++pass) {
    __syncthreads();
    if ((wave & 1) == pass) {
#pragma unroll
      for (int mt = 0; mt < 4; mt++)
#pragma unroll
        for (int nt = 0; nt < 4; nt++)
#pragma unroll
          for (int r = 0; r < 4; r++)
            Cs[(mt * 16 + lq4 + r) * 130 + wn + nt * 16 + lrow] =
                __float2bfloat16(acc[mt][nt][r]);
    }
    __syncthreads();
    if (seg < 2) {
      __hip_bfloat16* Out = seg ? Kr : Qr;
#pragma unroll
      for (int p = 0; p < 2; ++p) {
        const int row = (tid >> 3) + p * 32;
        const int oct = (tid & 7) * 8;
        const int m = m0 + pass * 64 + row;
        const float pos = (float)(m & 2047);
        alignas(16) __hip_bfloat16 lo[8], hi[8];
#pragma unroll
        for (int k2 = 0; k2 < 8; k2++) {
          const float ang = pos * invf[oct + k2];
          float sn, cs2;
          __sincosf(ang, &sn, &cs2);
          const float a  = __bfloat162float(Cs[row * 130 + oct + k2]);
          const float bb = __bfloat162float(Cs[row * 130 + oct + k2 + 64]);
          lo[k2] = __float2bfloat16((a * cs2 - bb * sn) * qscale);
          hi[k2] = __float2bfloat16((bb * cs2 + a * sn) * qscale);
        }
        const size_t ob = ((size_t)bh * 2048 + (size_t)(m & 2047)) * 128;
        *(bf16x8*)&Out[ob + oct]      = *(const bf16x8*)lo;
        *(bf16x8*)&Out[ob + oct + 64] = *(const bf16x8*)hi;
      }
    } else {
#pragma unroll
      for (int p = 0; p < 4; ++p) {
        const int d = (tid >> 3) + p * 32;
        const int s8 = (tid & 7) * 8;
        alignas(16) __hip_bfloat16 tmp[8];
#pragma unroll
        for (int k2 = 0; k2 < 8; k2++) tmp[k2] = Cs[(s8 + k2) * 130 + d];
        const size_t ob = ((size_t)bh * 128 + d) * 2048 + seq0 + pass * 64 + s8;
        *(bf16x8*)&Vt[ob] = *(const bf16x8*)tmp;
      }
    }
  }
}

// ---------------- sliding-window flash attention, direct-from-L2 ----------------
// 64 q-rows/block, 4 waves, no barriers in the key loop, no K/V LDS staging.
// S^T = K*Q^T (operand swap); fragments loaded straight from global (L1/L2-hit);
// Pb wave-private for the P C->A layout round-trip.
__global__ __launch_bounds__(256, 4)
void attn_swa(const __hip_bfloat16* __restrict__ Qr, const __hip_bfloat16* __restrict__ Kr,
              const __hip_bfloat16* __restrict__ Vt, __hip_bfloat16* __restrict__ Out)
{
  __shared__ __hip_bfloat16 Pb[4][16 * 72];  // per-wave P[i][j], stride 72 (16B-aligned rows)
  const int qt = blockIdx.x, bh = blockIdx.y;
  const int tid = threadIdx.x, lane = tid & 63, wave = tid >> 6;
  const int lrow = lane & 15, lk = (lane >> 4) * 8, lq4 = (lane >> 4) * 4;
  const int i0 = qt * 64;
  const float NEG_INF = -__builtin_inff();
  const __hip_bfloat16* Qh = Qr + (size_t)bh * 2048 * 128;
  const __hip_bfloat16* Kh = Kr + (size_t)bh * 2048 * 128;
  const __hip_bfloat16* Vh = Vt + (size_t)bh * 128 * 2048;

  // Q fragments straight from global (row = this lane's q-row for the A/B-frag k-slices)
  const int iw = i0 + wave * 16 + lrow;       // this lane's q row
  bf16x8 qf[4];
#pragma unroll
  for (int ks = 0; ks < 4; ks++)
    qf[ks] = *(const bf16x8*)&Qh[(size_t)iw * 128 + ks * 32 + lk];

  floatx4 accO[8] = {};
  float m_i = NEG_INF, l_i = 0.f;
  const int imin = i0 + wave * 16;
  const int lo = i0 - 511;
  const int jt_lo = (lo > 0 ? lo : 0) >> 6;
  const int jt_hi = i0 >> 6;                  // i0+63 within tile qt

  for (int jt = jt_lo; jt <= jt_hi; jt++) {
    const int j0 = jt * 64;
    // S^T[j][i] = sum_d K[j][d] Q[i][d]  (A=K-frag from global, B=Q-frag regs)
    floatx4 s[4] = {};
#pragma unroll
    for (int nt = 0; nt < 4; nt++) {
      const size_t krow = (size_t)(j0 + nt * 16 + lrow) * 128;
#pragma unroll
      for (int ks = 0; ks < 4; ks++) {
        const bf16x8 kf = *(const bf16x8*)&Kh[krow + ks * 32 + lk];
        s[nt] = __builtin_amdgcn_mfma_f32_16x16x32_bf16(kf, qf[ks], s[nt], 0, 0, 0);
      }
    }
    // lane holds: i = iw (fixed), j = j0 + nt*16 + lq4 + r
    const bool full = (j0 + 63 <= imin) && (j0 >= imin + 15 - 511);
    float rmax = NEG_INF;
    if (full) {
#pragma unroll
      for (int nt = 0; nt < 4; nt++)
#pragma unroll
        for (int r = 0; r < 4; r++) rmax = fmaxf(rmax, s[nt][r]);
    } else {
#pragma unroll
      for (int nt = 0; nt < 4; nt++) {
#pragma unroll
        for (int r = 0; r < 4; r++) {
          const int j = j0 + nt * 16 + lq4 + r;
          const float sv = ((j <= iw) && (j > iw - 512)) ? s[nt][r] : NEG_INF;
          s[nt][r] = sv;
          rmax = fmaxf(rmax, sv);
        }
      }
    }
    rmax = fmaxf(rmax, __shfl_xor(rmax, 16));
    rmax = fmaxf(rmax, __shfl_xor(rmax, 32));
    const float mnew = fmaxf(m_i, rmax);
    const float alpha = __expf(fminf(m_i - mnew, 0.f));  // guards (-inf)-(-inf)
    m_i = mnew;
    float rs = 0.f;
    if (full) {
#pragma unroll
      for (int nt = 0; nt < 4; nt++)
#pragma unroll
        for (int r = 0; r < 4; r++) {
          const float p = __expf(s[nt][r] - mnew);
          s[nt][r] = p;
          rs += p;
        }
    } else {
#pragma unroll
      for (int nt = 0; nt < 4; nt++)
#pragma unroll
        for (int r = 0; r < 4; r++) {
          const float sv = s[nt][r];
          const float p = (sv == NEG_INF) ? 0.f : __expf(sv - mnew);
          s[nt][r] = p;
          rs += p;
        }
    }
    rs += __shfl_xor(rs, 16);
    rs += __shfl_xor(rs, 32);
    l_i = l_i * alpha + rs;
#pragma unroll
    for (int dt = 0; dt < 8; dt++) accO[dt] *= alpha;
    // P^T -> Pb[i][j] packed b64 (wave-private; same-wave LDS ops are ordered)
#pragma unroll
    for (int nt = 0; nt < 4; nt++) {
      alignas(8) __hip_bfloat16 p4[4];
#pragma unroll
      for (int r = 0; r < 4; r++) p4[r] = __float2bfloat16(s[nt][r]);
      *(uint64_t*)&Pb[wave][lrow * 72 + nt * 16 + lq4] = *(const uint64_t*)p4;
    }
    bf16x8 pf[2];
#pragma unroll
    for (int jf = 0; jf < 2; jf++)
      pf[jf] = *(const bf16x8*)&Pb[wave][lrow * 72 + jf * 32 + lk];
    // O^T[d][i] += sum_j V^T[d][j] P[i][j]  (A=V^T-frag from global, B=P-frag)
#pragma unroll
    for (int dt = 0; dt < 8; dt++) {
      const size_t vrow = (size_t)(dt * 16 + lrow) * 2048 + j0;
#pragma unroll
      for (int jf = 0; jf < 2; jf++) {
        const bf16x8 vf = *(const bf16x8*)&Vh[vrow + jf * 32 + lk];
        accO[dt] = __builtin_amdgcn_mfma_f32_16x16x32_bf16(vf, pf[jf], accO[dt], 0, 0, 0);
      }
    }
  }
  // write: lane has O^T[d = dt*16+lq4+r][i = iw]; pack 4 consecutive d as 8B
  const int b = bh >> 4, h = bh & 15;
  const float inv_l = 1.0f / l_i;
  const size_t rowb = ((size_t)(b * 2048 + iw)) * 2048 + h * 128;
#pragma unroll
  for (int dt = 0; dt < 8; dt++) {
    alignas(8) __hip_bfloat16 o4[4];
#pragma unroll
    for (int r = 0; r < 4; r++) o4[r] = __float2bfloat16(accO[dt][r] * inv_l);
    *(uint64_t*)&Out[rowb + dt * 16 + lq4] = *(const uint64_t*)o4;
  }
}

// ---------------- launch ----------------
extern "C" void kernel_launch(void* const* d_in, const int* in_sizes, int n_in,
                              void* d_out, int out_size, void* d_ws, size_t ws_size,
                              hipStream_t stream)
{
  const float* x = (const float*)d_in[0];      // [2,2048,2048]
  const float* w_qkv = (const float*)d_in[1];  // [6144,2048]
  const float* w_o = (const float*)d_in[2];    // [2048,2048]
  float* y = (float*)d_out;                    // [2,2048,2048] fp32
  char* ws = (char*)d_ws;

  const size_t SZ_X = 16777216;     // 4096*2048*2 B
  const size_t SZ_WQKV = 25165824;  // 6144*2048*2 B
  const size_t SZ_Q = 16777216;     // 32*2048*128*2 B

  __hip_bfloat16* xb = (__hip_bfloat16*)(ws);            // x bf16; later attn out
  __hip_bfloat16* wqkvb = (__hip_bfloat16*)(ws + SZ_X);  // w_qkv bf16; later w_o bf16
  __hip_bfloat16* Qr = (__hip_bfloat16*)(ws + SZ_X + SZ_WQKV);
  __hip_bfloat16* Kr = (__hip_bfloat16*)(ws + SZ_X + SZ_WQKV + SZ_Q);
  __hip_bfloat16* Vt = (__hip_bfloat16*)(ws + SZ_X + SZ_WQKV + 2 * SZ_Q);

  cvt_kernel<<<dim3(8192), dim3(256), 0, stream>>>(x, xb, 8388608);
  cvt_kernel<<<dim3(12288), dim3(256), 0, stream>>>(w_qkv, wqkvb, 12582912);
  gemm_qkv_fused<<<dim3(32, 48), dim3(256), 0, stream>>>(xb, wqkvb, Qr, Kr, Vt);
  attn_swa<<<dim3(32, 32), dim3(256), 0, stream>>>(Qr, Kr, Vt, xb /*attn_out*/);
  cvt_kernel<<<dim3(4096), dim3(256), 0, stream>>>(w_o, wqkvb, 4194304);
  gemm_bt<<<dim3(32, 16), dim3(256), 0, stream>>>(xb, wqkvb, (void*)y, 4096, 2048, 2048, 1);
}

// Round 5
// 385.414 us; speedup vs baseline: 1.1928x; 1.1928x over previous
//
#include <hip/hip_runtime.h>
#include <hip/hip_bf16.h>
#include <cstdint>

typedef __bf16 bf16x8 __attribute__((ext_vector_type(8)));
typedef float floatx4 __attribute__((ext_vector_type(4)));

__device__ __forceinline__ void gl2lds16(const void* g, void* l) {
  __builtin_amdgcn_global_load_lds(
      (const __attribute__((address_space(1))) unsigned int*)g,
      (__attribute__((address_space(3))) unsigned int*)(uintptr_t)l,
      16, 0, 0);
}

// ---------------- fp32 -> bf16 convert ----------------
__global__ __launch_bounds__(256)
void cvt_kernel(const float* __restrict__ in, __hip_bfloat16* __restrict__ out, int n) {
  int i = (blockIdx.x * 256 + threadIdx.x) * 4;
  if (i >= n) return;
  const float4 v = *(const float4*)(in + i);
  out[i + 0] = __float2bfloat16(v.x);
  out[i + 1] = __float2bfloat16(v.y);
  out[i + 2] = __float2bfloat16(v.z);
  out[i + 3] = __float2bfloat16(v.w);
}

// ---------------- plain bf16 GEMM (O-proj): C[M][Nc] = A[M][K] * B[Nc][K]^T ----
__global__ __launch_bounds__(256)
void gemm_bt(const __hip_bfloat16* __restrict__ A, const __hip_bfloat16* __restrict__ Bm,
             void* __restrict__ Cp, int M, int Nc, int K, int c_fp32)
{
  __shared__ __hip_bfloat16 As[128 * 32];
  __shared__ __hip_bfloat16 Bs[128 * 32];
  const int tid = threadIdx.x;
  const int lane = tid & 63, wave = tid >> 6;
  const int wm = (wave & 1) * 64, wn = (wave >> 1) * 64;
  const int m0 = blockIdx.x * 128, n0 = blockIdx.y * 128;
  const int lrow = lane & 15, lk = (lane >> 4) * 8;
  floatx4 acc[4][4] = {};
  const int c0 = tid, c1 = tid + 256;
  const int r0 = c0 >> 2, o0 = (c0 & 3) * 8;
  const int r1 = c1 >> 2, o1 = (c1 & 3) * 8;
  for (int kt = 0; kt < K; kt += 32) {
    __syncthreads();
    gl2lds16(A + (size_t)(m0 + r0) * K + kt + o0, &As[c0 * 8]);
    gl2lds16(A + (size_t)(m0 + r1) * K + kt + o1, &As[c1 * 8]);
    gl2lds16(Bm + (size_t)(n0 + r0) * K + kt + o0, &Bs[c0 * 8]);
    gl2lds16(Bm + (size_t)(n0 + r1) * K + kt + o1, &Bs[c1 * 8]);
    __syncthreads();
    bf16x8 af[4], bfr[4];
#pragma unroll
    for (int t = 0; t < 4; t++) af[t] = *(const bf16x8*)&As[(wm + t * 16 + lrow) * 32 + lk];
#pragma unroll
    for (int t = 0; t < 4; t++) bfr[t] = *(const bf16x8*)&Bs[(wn + t * 16 + lrow) * 32 + lk];
#pragma unroll
    for (int mt = 0; mt < 4; mt++)
#pragma unroll
      for (int nt = 0; nt < 4; nt++)
        acc[mt][nt] = __builtin_amdgcn_mfma_f32_16x16x32_bf16(af[mt], bfr[nt], acc[mt][nt], 0, 0, 0);
  }
  const int lq4 = (lane >> 4) * 4;
#pragma unroll
  for (int mt = 0; mt < 4; mt++)
#pragma unroll
    for (int nt = 0; nt < 4; nt++)
#pragma unroll
      for (int r = 0; r < 4; r++) {
        const int m = m0 + wm + mt * 16 + lq4 + r;
        const int n = n0 + wn + nt * 16 + lrow;
        const float v = acc[mt][nt][r];
        if (c_fp32) ((float*)Cp)[(size_t)m * Nc + n] = v;
        else ((__hip_bfloat16*)Cp)[(size_t)m * Nc + n] = __float2bfloat16(v);
      }
}

// ---------------- QKV GEMM with fused RoPE + relayout epilogue ----------------
__global__ __launch_bounds__(256)
void gemm_qkv_fused(const __hip_bfloat16* __restrict__ A,
                    const __hip_bfloat16* __restrict__ W,
                    __hip_bfloat16* __restrict__ Qr,
                    __hip_bfloat16* __restrict__ Kr,
                    __hip_bfloat16* __restrict__ Vt)
{
  __shared__ alignas(16) char smem[16640];     // union: As+Bs (16384) | Cs 64x130 bf16 (16640)
  __shared__ float invf[64];
  __hip_bfloat16* As = (__hip_bfloat16*)smem;
  __hip_bfloat16* Bs = As + 128 * 32;
  __hip_bfloat16* Cs = (__hip_bfloat16*)smem;  // [64][130]
  const int tid = threadIdx.x;
  if (tid < 64) invf[tid] = __expf(-(float)tid * 0.14391156831212787f);  // 10000^(-t/64)
  const int lane = tid & 63, wave = tid >> 6;
  const int wm = (wave & 1) * 64, wn = (wave >> 1) * 64;
  const int m0 = blockIdx.x * 128, n0 = blockIdx.y * 128;
  const int K = 2048;
  const int lrow = lane & 15, lk = (lane >> 4) * 8;
  floatx4 acc[4][4] = {};
  const int c0 = tid, c1 = tid + 256;
  const int r0 = c0 >> 2, o0 = (c0 & 3) * 8;
  const int r1 = c1 >> 2, o1 = (c1 & 3) * 8;
  for (int kt = 0; kt < K; kt += 32) {
    __syncthreads();
    gl2lds16(A + (size_t)(m0 + r0) * K + kt + o0, &As[c0 * 8]);
    gl2lds16(A + (size_t)(m0 + r1) * K + kt + o1, &As[c1 * 8]);
    gl2lds16(W + (size_t)(n0 + r0) * K + kt + o0, &Bs[c0 * 8]);
    gl2lds16(W + (size_t)(n0 + r1) * K + kt + o1, &Bs[c1 * 8]);
    __syncthreads();
    bf16x8 af[4], bfr[4];
#pragma unroll
    for (int t = 0; t < 4; t++) af[t] = *(const bf16x8*)&As[(wm + t * 16 + lrow) * 32 + lk];
#pragma unroll
    for (int t = 0; t < 4; t++) bfr[t] = *(const bf16x8*)&Bs[(wn + t * 16 + lrow) * 32 + lk];
#pragma unroll
    for (int mt = 0; mt < 4; mt++)
#pragma unroll
      for (int nt = 0; nt < 4; nt++)
        acc[mt][nt] = __builtin_amdgcn_mfma_f32_16x16x32_bf16(af[mt], bfr[nt], acc[mt][nt], 0, 0, 0);
  }
  const int lq4 = (lane >> 4) * 4;
  const int seg = n0 >> 11;            // 0=Q 1=K 2=V
  const int h = (n0 & 2047) >> 7;
  const int b = m0 >> 11;
  const int bh = b * 16 + h;
  const int seq0 = m0 & 2047;
  const float qscale = (seg == 0) ? 0.08838834764831845f : 1.0f;
  for (int pass = 0; pass < 2; ++pass) {
    __syncthreads();
    if ((wave & 1) == pass) {
#pragma unroll
      for (int mt = 0; mt < 4; mt++)
#pragma unroll
        for (int nt = 0; nt < 4; nt++)
#pragma unroll
          for (int r = 0; r < 4; r++)
            Cs[(mt * 16 + lq4 + r) * 130 + wn + nt * 16 + lrow] =
                __float2bfloat16(acc[mt][nt][r]);
    }
    __syncthreads();
    if (seg < 2) {
      __hip_bfloat16* Out = seg ? Kr : Qr;
#pragma unroll
      for (int p = 0; p < 2; ++p) {
        const int row = (tid >> 3) + p * 32;
        const int oct = (tid & 7) * 8;
        const int m = m0 + pass * 64 + row;
        const float pos = (float)(m & 2047);
        alignas(16) __hip_bfloat16 lo[8], hi[8];
#pragma unroll
        for (int k2 = 0; k2 < 8; k2++) {
          const float ang = pos * invf[oct + k2];
          float sn, cs2;
          __sincosf(ang, &sn, &cs2);
          const float a  = __bfloat162float(Cs[row * 130 + oct + k2]);
          const float bb = __bfloat162float(Cs[row * 130 + oct + k2 + 64]);
          lo[k2] = __float2bfloat16((a * cs2 - bb * sn) * qscale);
          hi[k2] = __float2bfloat16((bb * cs2 + a * sn) * qscale);
        }
        const size_t ob = ((size_t)bh * 2048 + (size_t)(m & 2047)) * 128;
        *(bf16x8*)&Out[ob + oct]      = *(const bf16x8*)lo;
        *(bf16x8*)&Out[ob + oct + 64] = *(const bf16x8*)hi;
      }
    } else {
#pragma unroll
      for (int p = 0; p < 4; ++p) {
        const int d = (tid >> 3) + p * 32;
        const int s8 = (tid & 7) * 8;
        alignas(16) __hip_bfloat16 tmp[8];
#pragma unroll
        for (int k2 = 0; k2 < 8; k2++) tmp[k2] = Cs[(s8 + k2) * 130 + d];
        const size_t ob = ((size_t)bh * 128 + d) * 2048 + seq0 + pass * 64 + s8;
        *(bf16x8*)&Vt[ob] = *(const bf16x8*)tmp;
      }
    }
  }
}

// ---------------- sliding-window flash attention, pipelined reg->LDS staging ---
// 128 q-rows/block, 8 waves; S^T = K*Q^T; padded LDS strides (no bank conflicts);
// global->reg loads for tile jt+1 issued before a raw (non-vmcnt-draining)
// barrier so they overlap compute of tile jt.
#define KSTR 136   // K tile row stride (elems): 272B -> bank-start lrow*4 (mod 32)
#define VSTR 72    // V/P tile row stride: 144B -> bank-start lrow*4 (mod 32)
__global__ __launch_bounds__(512, 4)
void attn_swa(const __hip_bfloat16* __restrict__ Qr, const __hip_bfloat16* __restrict__ Kr,
              const __hip_bfloat16* __restrict__ Vt, __hip_bfloat16* __restrict__ Out)
{
  __shared__ __hip_bfloat16 Ks[64 * KSTR];
  __shared__ __hip_bfloat16 Vs[128 * VSTR];
  __shared__ __hip_bfloat16 Pb[8][16 * VSTR];
  const int qt = blockIdx.x, bh = blockIdx.y;
  const int tid = threadIdx.x, lane = tid & 63, wave = tid >> 6;
  const int lrow = lane & 15, lk = (lane >> 4) * 8, lq4 = (lane >> 4) * 4;
  const int i0 = qt * 128;
  const float NEG_INF = -__builtin_inff();
  const __hip_bfloat16* Qh = Qr + (size_t)bh * 2048 * 128;
  const __hip_bfloat16* Kh = Kr + (size_t)bh * 2048 * 128;
  const __hip_bfloat16* Vh = Vt + (size_t)bh * 128 * 2048;

  // staging slot assignment (per thread: 2 K granules + 2 V granules)
  const int ck0 = tid, ck1 = tid + 512;          // K slots: row=c>>4, g=c&15
  const int kr0 = ck0 >> 4, kg0 = (ck0 & 15) * 8;
  const int kr1 = ck1 >> 4, kg1 = (ck1 & 15) * 8;
  const int cv0 = tid, cv1 = tid + 512;          // V slots: d=c>>3, col=(c&7)*8
  const int vd0 = cv0 >> 3, vc0 = (cv0 & 7) * 8;
  const int vd1 = cv1 >> 3, vc1 = (cv1 & 7) * 8;

  // Q fragments straight from global (one-time)
  const int iw = i0 + wave * 16 + lrow;          // this lane's q row
  bf16x8 qf[4];
#pragma unroll
  for (int ks = 0; ks < 4; ks++)
    qf[ks] = *(const bf16x8*)&Qh[(size_t)iw * 128 + ks * 32 + lk];

  floatx4 accO[8] = {};
  float m_i = NEG_INF, l_i = 0.f;
  const int imin = i0 + wave * 16;
  const int lo = i0 - 511;
  const int jt_lo = (lo > 0 ? lo : 0) >> 6;
  const int jt_hi = (i0 + 127) >> 6;

  // prefetch tile jt_lo into registers
  int j0n = jt_lo * 64;
  int4 rk0 = *(const int4*)&Kh[(size_t)(j0n + kr0) * 128 + kg0];
  int4 rk1 = *(const int4*)&Kh[(size_t)(j0n + kr1) * 128 + kg1];
  int4 rv0 = *(const int4*)&Vh[(size_t)vd0 * 2048 + j0n + vc0];
  int4 rv1 = *(const int4*)&Vh[(size_t)vd1 * 2048 + j0n + vc1];

  for (int jt = jt_lo; jt <= jt_hi; jt++) {
    const int j0 = jt * 64;
    __syncthreads();  // all waves done reading prev tile; drains vmcnt -> regs ready
    *(int4*)&Ks[kr0 * KSTR + kg0] = rk0;
    *(int4*)&Ks[kr1 * KSTR + kg1] = rk1;
    *(int4*)&Vs[vd0 * VSTR + vc0] = rv0;
    *(int4*)&Vs[vd1 * VSTR + vc1] = rv1;
    if (jt < jt_hi) {  // issue next tile's loads; they stay in flight through compute
      const int jn = j0 + 64;
      rk0 = *(const int4*)&Kh[(size_t)(jn + kr0) * 128 + kg0];
      rk1 = *(const int4*)&Kh[(size_t)(jn + kr1) * 128 + kg1];
      rv0 = *(const int4*)&Vh[(size_t)vd0 * 2048 + jn + vc0];
      rv1 = *(const int4*)&Vh[(size_t)vd1 * 2048 + jn + vc1];
    }
    // raw barrier: wait LDS writes only (lgkmcnt(0)), leave vmcnt in flight
    asm volatile("" ::: "memory");
    __builtin_amdgcn_s_waitcnt(0xC07F);  // vmcnt=max, expcnt=max, lgkmcnt=0
    __builtin_amdgcn_s_barrier();
    asm volatile("" ::: "memory");

    // S^T[j][i] = sum_d K[j][d] Q[i][d]
    floatx4 s[4] = {};
#pragma unroll
    for (int nt = 0; nt < 4; nt++) {
      const int krow = (nt * 16 + lrow) * KSTR;
#pragma unroll
      for (int ks = 0; ks < 4; ks++) {
        const bf16x8 kf = *(const bf16x8*)&Ks[krow + ks * 32 + lk];
        s[nt] = __builtin_amdgcn_mfma_f32_16x16x32_bf16(kf, qf[ks], s[nt], 0, 0, 0);
      }
    }
    // lane holds: i = iw (fixed), j = j0 + nt*16 + lq4 + r
    const bool full = (j0 + 63 <= imin) && (j0 >= imin + 15 - 511);
    float rmax = NEG_INF;
    if (full) {
#pragma unroll
      for (int nt = 0; nt < 4; nt++)
#pragma unroll
        for (int r = 0; r < 4; r++) rmax = fmaxf(rmax, s[nt][r]);
    } else {
#pragma unroll
      for (int nt = 0; nt < 4; nt++) {
#pragma unroll
        for (int r = 0; r < 4; r++) {
          const int j = j0 + nt * 16 + lq4 + r;
          const float sv = ((j <= iw) && (j > iw - 512)) ? s[nt][r] : NEG_INF;
          s[nt][r] = sv;
          rmax = fmaxf(rmax, sv);
        }
      }
    }
    rmax = fmaxf(rmax, __shfl_xor(rmax, 16));
    rmax = fmaxf(rmax, __shfl_xor(rmax, 32));
    const float mnew = fmaxf(m_i, rmax);
    const float alpha = __expf(fminf(m_i - mnew, 0.f));  // guards (-inf)-(-inf)
    m_i = mnew;
    float rs = 0.f;
    if (full) {
#pragma unroll
      for (int nt = 0; nt < 4; nt++)
#pragma unroll
        for (int r = 0; r < 4; r++) {
          const float p = __expf(s[nt][r] - mnew);
          s[nt][r] = p;
          rs += p;
        }
    } else {
#pragma unroll
      for (int nt = 0; nt < 4; nt++)
#pragma unroll
        for (int r = 0; r < 4; r++) {
          const float sv = s[nt][r];
          const float p = (sv == NEG_INF) ? 0.f : __expf(sv - mnew);
          s[nt][r] = p;
          rs += p;
        }
    }
    rs += __shfl_xor(rs, 16);
    rs += __shfl_xor(rs, 32);
    l_i = l_i * alpha + rs;
#pragma unroll
    for (int dt = 0; dt < 8; dt++) accO[dt] *= alpha;
    // P^T -> Pb[i][j] packed b64 (wave-private; same-wave LDS ops ordered)
#pragma unroll
    for (int nt = 0; nt < 4; nt++) {
      alignas(8) __hip_bfloat16 p4[4];
#pragma unroll
      for (int r = 0; r < 4; r++) p4[r] = __float2bfloat16(s[nt][r]);
      *(uint64_t*)&Pb[wave][lrow * VSTR + nt * 16 + lq4] = *(const uint64_t*)p4;
    }
    bf16x8 pf[2];
#pragma unroll
    for (int jf = 0; jf < 2; jf++)
      pf[jf] = *(const bf16x8*)&Pb[wave][lrow * VSTR + jf * 32 + lk];
    // O^T[d][i] += sum_j V^T[d][j] P[i][j]
#pragma unroll
    for (int dt = 0; dt < 8; dt++) {
      const int vrow = (dt * 16 + lrow) * VSTR;
#pragma unroll
      for (int jf = 0; jf < 2; jf++) {
        const bf16x8 vf = *(const bf16x8*)&Vs[vrow + jf * 32 + lk];
        accO[dt] = __builtin_amdgcn_mfma_f32_16x16x32_bf16(vf, pf[jf], accO[dt], 0, 0, 0);
      }
    }
  }
  // write: lane has O^T[d = dt*16+lq4+r][i = iw]; pack 4 consecutive d as 8B
  const int b = bh >> 4, h = bh & 15;
  const float inv_l = 1.0f / l_i;
  const size_t rowb = ((size_t)(b * 2048 + iw)) * 2048 + h * 128;
#pragma unroll
  for (int dt = 0; dt < 8; dt++) {
    alignas(8) __hip_bfloat16 o4[4];
#pragma unroll
    for (int r = 0; r < 4; r++) o4[r] = __float2bfloat16(accO[dt][r] * inv_l);
    *(uint64_t*)&Out[rowb + dt * 16 + lq4] = *(const uint64_t*)o4;
  }
}

// ---------------- launch ----------------
extern "C" void kernel_launch(void* const* d_in, const int* in_sizes, int n_in,
                              void* d_out, int out_size, void* d_ws, size_t ws_size,
                              hipStream_t stream)
{
  const float* x = (const float*)d_in[0];      // [2,2048,2048]
  const float* w_qkv = (const float*)d_in[1];  // [6144,2048]
  const float* w_o = (const float*)d_in[2];    // [2048,2048]
  float* y = (float*)d_out;                    // [2,2048,2048] fp32
  char* ws = (char*)d_ws;

  const size_t SZ_X = 16777216;     // 4096*2048*2 B
  const size_t SZ_WQKV = 25165824;  // 6144*2048*2 B
  const size_t SZ_Q = 16777216;     // 32*2048*128*2 B

  __hip_bfloat16* xb = (__hip_bfloat16*)(ws);            // x bf16; later attn out
  __hip_bfloat16* wqkvb = (__hip_bfloat16*)(ws + SZ_X);  // w_qkv bf16; later w_o bf16
  __hip_bfloat16* Qr = (__hip_bfloat16*)(ws + SZ_X + SZ_WQKV);
  __hip_bfloat16* Kr = (__hip_bfloat16*)(ws + SZ_X + SZ_WQKV + SZ_Q);
  __hip_bfloat16* Vt = (__hip_bfloat16*)(ws + SZ_X + SZ_WQKV + 2 * SZ_Q);

  cvt_kernel<<<dim3(8192), dim3(256), 0, stream>>>(x, xb, 8388608);
  cvt_kernel<<<dim3(12288), dim3(256), 0, stream>>>(w_qkv, wqkvb, 12582912);
  gemm_qkv_fused<<<dim3(32, 48), dim3(256), 0, stream>>>(xb, wqkvb, Qr, Kr, Vt);
  attn_swa<<<dim3(16, 32), dim3(512), 0, stream>>>(Qr, Kr, Vt, xb /*attn_out*/);
  cvt_kernel<<<dim3(4096), dim3(256), 0, stream>>>(w_o, wqkvb, 4194304);
  gemm_bt<<<dim3(32, 16), dim3(256), 0, stream>>>(xb, wqkvb, (void*)y, 4096, 2048, 2048, 1);
}